// Round 1
// baseline (984.075 us; speedup 1.0000x reference)
//
#include <hip/hip_runtime.h>

#define NNODES 50000
#define HEADS 3

__device__ __forceinline__ float wred_max(float v){
  #pragma unroll
  for (int s = 32; s > 0; s >>= 1) v = fmaxf(v, __shfl_xor(v, s, 64));
  return v;
}
__device__ __forceinline__ float wred_sum(float v){
  #pragma unroll
  for (int s = 32; s > 0; s >>= 1) v += __shfl_xor(v, s, 64);
  return v;
}

// ---------------- GEMM: C[M,NC] = A[M,K] @ B[K,NC], fp32 ----------------
// 64x64 tile, 256 threads, 4x4 microtile, K-chunk 32, k-major A in LDS (+4 pad)
__global__ __launch_bounds__(256) void gemm_kernel(
    const float* __restrict__ A, const float* __restrict__ B,
    float* __restrict__ C, int M, int K, int NC)
{
  __shared__ __align__(16) float a_s[32][68];
  __shared__ __align__(16) float b_s[32][68];
  const int tid  = threadIdx.x;
  const int row0 = blockIdx.x * 64;
  const int col0 = blockIdx.y * 64;
  const int tx = tid & 15, ty = tid >> 4;
  float acc[4][4] = {};

  for (int kc = 0; kc < K; kc += 32) {
    #pragma unroll
    for (int p = 0; p < 2; ++p) {
      int idx = tid + p * 256;
      int r = idx >> 3, kg = (idx & 7) << 2;
      float4 v = make_float4(0.f, 0.f, 0.f, 0.f);
      int gr = row0 + r;
      if (gr < M) v = *(const float4*)&A[(size_t)gr * K + kc + kg];
      a_s[kg + 0][r] = v.x; a_s[kg + 1][r] = v.y;
      a_s[kg + 2][r] = v.z; a_s[kg + 3][r] = v.w;
    }
    #pragma unroll
    for (int p = 0; p < 2; ++p) {
      int idx = tid + p * 256;
      int kr = idx >> 4, cg = (idx & 15) << 2;
      float4 v = make_float4(0.f, 0.f, 0.f, 0.f);
      if (col0 + cg + 3 < NC) v = *(const float4*)&B[(size_t)(kc + kr) * NC + col0 + cg];
      *(float4*)&b_s[kr][cg] = v;
    }
    __syncthreads();
    #pragma unroll
    for (int k = 0; k < 32; ++k) {
      float4 va4 = *(const float4*)&a_s[k][ty << 2];
      float4 vb4 = *(const float4*)&b_s[k][tx << 2];
      float av[4] = {va4.x, va4.y, va4.z, va4.w};
      float bv[4] = {vb4.x, vb4.y, vb4.z, vb4.w};
      #pragma unroll
      for (int i = 0; i < 4; ++i)
        #pragma unroll
        for (int j = 0; j < 4; ++j)
          acc[i][j] += av[i] * bv[j];
    }
    __syncthreads();
  }
  #pragma unroll
  for (int i = 0; i < 4; ++i) {
    int gr = row0 + (ty << 2) + i;
    if (gr < M && col0 + (tx << 2) + 3 < NC) {
      float4 v = make_float4(acc[i][0], acc[i][1], acc[i][2], acc[i][3]);
      *(float4*)&C[(size_t)gr * NC + col0 + (tx << 2)] = v;
    }
  }
}

// ---------------- el/er: one wave per (node, head) ----------------
__global__ __launch_bounds__(256) void attn_coef_kernel(
    const float* __restrict__ feat, const float* __restrict__ al,
    const float* __restrict__ ar, float* __restrict__ el, float* __restrict__ er,
    int N, int F)
{
  int wid  = blockIdx.x * 4 + (threadIdx.x >> 6);
  int lane = threadIdx.x & 63;
  if (wid >= N * HEADS) return;
  int n = wid / HEADS, h = wid - n * HEADS;
  float v = 0.f, a = 0.f, b = 0.f;
  if (lane < F) {
    v = feat[(size_t)n * (HEADS * F) + h * F + lane];
    a = al[h * F + lane];
    b = ar[h * F + lane];
  }
  float se = wred_sum(v * a);
  float sr = wred_sum(v * b);
  if (lane == 0) { el[n * HEADS + h] = se; er[n * HEADS + h] = sr; }
}

// ---------------- CSR build ----------------
__global__ __launch_bounds__(256) void count_deg_kernel(
    const int* __restrict__ dst, int* __restrict__ deg, int E)
{
  for (int i = blockIdx.x * blockDim.x + threadIdx.x; i < E; i += gridDim.x * blockDim.x)
    atomicAdd(&deg[dst[i]], 1);
}

__global__ __launch_bounds__(1024) void scan_kernel(
    const int* __restrict__ deg, int* __restrict__ off, int n)
{
  __shared__ int tmp[1024];
  __shared__ int carry;
  int t = threadIdx.x;
  if (t == 0) carry = 0;
  __syncthreads();
  for (int base = 0; base <= n; base += 1024) {
    int i = base + t;
    int v = (i < n) ? deg[i] : 0;
    tmp[t] = v;
    __syncthreads();
    for (int s = 1; s < 1024; s <<= 1) {
      int a = (t >= s) ? tmp[t - s] : 0;
      __syncthreads();
      tmp[t] += a;
      __syncthreads();
    }
    int incl = tmp[t];
    if (i <= n) off[i] = carry + incl - v;
    int ct = tmp[1023];
    __syncthreads();
    if (t == 0) carry += ct;
    __syncthreads();
  }
}

__global__ __launch_bounds__(256) void fill_adj_kernel(
    const int* __restrict__ src, const int* __restrict__ dst,
    const int* __restrict__ off, int* __restrict__ cur, int* __restrict__ adj, int E)
{
  for (int i = blockIdx.x * blockDim.x + threadIdx.x; i < E; i += gridDim.x * blockDim.x) {
    int dn = dst[i];
    int p  = atomicAdd(&cur[dn], 1);
    adj[off[dn] + p] = src[i];
  }
}

// ---------------- aggregation: one wave per destination node ----------------
// mode 0: F=64, out = relu(agg) stored [N,192]
// mode 1: F=40, out = mean over heads stored [N,40]
__global__ __launch_bounds__(256) void aggregate_kernel(
    const float* __restrict__ feat, const int* __restrict__ adj,
    const int* __restrict__ off, const float* __restrict__ el,
    const float* __restrict__ er, float* __restrict__ out,
    int N, int F, int mode)
{
  int n    = blockIdx.x * 4 + (threadIdx.x >> 6);
  int lane = threadIdx.x & 63;
  if (n >= N) return;
  const int NC = HEADS * F;
  int o0 = off[n];
  int d  = off[n + 1] - o0;
  float er0 = er[n * 3 + 0], er1 = er[n * 3 + 1], er2 = er[n * 3 + 2];

  // pass A: per-head max
  float m0 = -1e30f, m1 = -1e30f, m2 = -1e30f;
  for (int i = lane; i < d; i += 64) {
    int s = adj[o0 + i];
    float x0 = el[s * 3 + 0] + er0; x0 = x0 > 0.f ? x0 : 0.2f * x0;
    float x1 = el[s * 3 + 1] + er1; x1 = x1 > 0.f ? x1 : 0.2f * x1;
    float x2 = el[s * 3 + 2] + er2; x2 = x2 > 0.f ? x2 : 0.2f * x2;
    m0 = fmaxf(m0, x0); m1 = fmaxf(m1, x1); m2 = fmaxf(m2, x2);
  }
  m0 = wred_max(m0); m1 = wred_max(m1); m2 = wred_max(m2);

  // pass B: per-head sum of exp
  float s0 = 0.f, s1 = 0.f, s2 = 0.f;
  for (int i = lane; i < d; i += 64) {
    int s = adj[o0 + i];
    float x0 = el[s * 3 + 0] + er0; x0 = x0 > 0.f ? x0 : 0.2f * x0;
    float x1 = el[s * 3 + 1] + er1; x1 = x1 > 0.f ? x1 : 0.2f * x1;
    float x2 = el[s * 3 + 2] + er2; x2 = x2 > 0.f ? x2 : 0.2f * x2;
    s0 += __expf(x0 - m0); s1 += __expf(x1 - m1); s2 += __expf(x2 - m2);
  }
  s0 = wred_sum(s0); s1 = wred_sum(s1); s2 = wred_sum(s2);
  float i0 = s0 > 0.f ? 1.f / s0 : 0.f;
  float i1 = s1 > 0.f ? 1.f / s1 : 0.f;
  float i2 = s2 > 0.f ? 1.f / s2 : 0.f;

  // pass C: weighted accumulation
  float a0 = 0.f, a1 = 0.f, a2 = 0.f;
  for (int base = 0; base < d; base += 64) {
    int i = base + lane;
    int ssrc = 0; float p0 = 0.f, p1 = 0.f, p2 = 0.f;
    if (i < d) {
      ssrc = adj[o0 + i];
      float x0 = el[ssrc * 3 + 0] + er0; x0 = x0 > 0.f ? x0 : 0.2f * x0;
      float x1 = el[ssrc * 3 + 1] + er1; x1 = x1 > 0.f ? x1 : 0.2f * x1;
      float x2 = el[ssrc * 3 + 2] + er2; x2 = x2 > 0.f ? x2 : 0.2f * x2;
      p0 = __expf(x0 - m0) * i0;
      p1 = __expf(x1 - m1) * i1;
      p2 = __expf(x2 - m2) * i2;
    }
    int cnt = min(64, d - base);
    for (int e = 0; e < cnt; ++e) {
      int   se = __shfl(ssrc, e, 64);
      float w0 = __shfl(p0, e, 64);
      float w1 = __shfl(p1, e, 64);
      float w2 = __shfl(p2, e, 64);
      const float* fr = feat + (size_t)se * NC;
      if (F == 64) {
        a0 += w0 * fr[lane];
        a1 += w1 * fr[64 + lane];
        a2 += w2 * fr[128 + lane];
      } else { // F == 40, NC = 120; lane holds elems {lane, 64+lane}
        float wa = lane < 40 ? w0 : w1;
        a0 += wa * fr[lane];
        if (lane < 56) {
          float wb = lane < 16 ? w1 : w2;
          a1 += wb * fr[64 + lane];
        }
      }
    }
  }

  if (mode == 0) {
    out[(size_t)n * 192 + lane]       = fmaxf(a0, 0.f);
    out[(size_t)n * 192 + 64 + lane]  = fmaxf(a1, 0.f);
    out[(size_t)n * 192 + 128 + lane] = fmaxf(a2, 0.f);
  } else {
    // combine heads: out[f] = (elem f + elem f+40 + elem f+80) / 3
    float t1 = __shfl(a0, lane + 40, 64);  // valid for lane < 24
    float t2 = __shfl(a1, lane - 24, 64);  // valid for lane >= 24
    float e2 = (lane < 24) ? t1 : t2;
    float e3 = __shfl(a1, lane + 16, 64);  // elem lane+80
    if (lane < 40) out[(size_t)n * 40 + lane] = (a0 + e2 + e3) * (1.0f / 3.0f);
  }
}

extern "C" void kernel_launch(void* const* d_in, const int* in_sizes, int n_in,
                              void* d_out, int out_size, void* d_ws, size_t ws_size,
                              hipStream_t stream) {
  const float* x   = (const float*)d_in[0];
  const int*   src = (const int*)d_in[1];
  const int*   dst = (const int*)d_in[2];
  const float* W0  = (const float*)d_in[3];
  const float* al0 = (const float*)d_in[4];
  const float* ar0 = (const float*)d_in[5];
  const float* W1  = (const float*)d_in[6];
  const float* al1 = (const float*)d_in[7];
  const float* ar1 = (const float*)d_in[8];
  const float* W2  = (const float*)d_in[9];
  const float* al2 = (const float*)d_in[10];
  const float* ar2 = (const float*)d_in[11];
  const int N = NNODES;
  const int E = in_sizes[1];
  float* out = (float*)d_out;

  char* w = (char*)d_ws;
  float* bufA = (float*)w; w += (size_t)N * 192 * 4;
  float* bufF = (float*)w; w += (size_t)N * 192 * 4;
  float* el   = (float*)w; w += (size_t)N * 3 * 4;
  float* er   = (float*)w; w += (size_t)N * 3 * 4;
  int* deg = (int*)w; w += (size_t)N * 4;
  int* off = (int*)w; w += (size_t)(N + 1) * 4;
  int* cur = (int*)w; w += (size_t)N * 4;
  int* adj = (int*)w; w += (size_t)E * 4;

  // CSR build (graph static across layers)
  hipMemsetAsync(deg, 0, (size_t)N * 4, stream);
  hipMemsetAsync(cur, 0, (size_t)N * 4, stream);
  count_deg_kernel<<<2048, 256, 0, stream>>>(dst, deg, E);
  scan_kernel<<<1, 1024, 0, stream>>>(deg, off, N);
  fill_adj_kernel<<<2048, 256, 0, stream>>>(src, dst, off, cur, adj, E);

  dim3 g01((N + 63) / 64, 3);
  dim3 g2((N + 63) / 64, 2);
  int cblk = (N * 3 + 3) / 4;
  int ablk = (N + 3) / 4;

  // layer 0
  gemm_kernel<<<g01, 256, 0, stream>>>(x, W0, bufF, N, 256, 192);
  attn_coef_kernel<<<cblk, 256, 0, stream>>>(bufF, al0, ar0, el, er, N, 64);
  aggregate_kernel<<<ablk, 256, 0, stream>>>(bufF, adj, off, el, er, bufA, N, 64, 0);
  // layer 1
  gemm_kernel<<<g01, 256, 0, stream>>>(bufA, W1, bufF, N, 192, 192);
  attn_coef_kernel<<<cblk, 256, 0, stream>>>(bufF, al1, ar1, el, er, N, 64);
  aggregate_kernel<<<ablk, 256, 0, stream>>>(bufF, adj, off, el, er, bufA, N, 64, 0);
  // layer 2
  gemm_kernel<<<g2, 256, 0, stream>>>(bufA, W2, bufF, N, 192, 120);
  attn_coef_kernel<<<cblk, 256, 0, stream>>>(bufF, al2, ar2, el, er, N, 40);
  aggregate_kernel<<<ablk, 256, 0, stream>>>(bufF, adj, off, el, er, out, N, 40, 1);
}

// Round 2
// 893.584 us; speedup vs baseline: 1.1013x; 1.1013x over previous
//
#include <hip/hip_runtime.h>

#define NNODES 50000
#define HEADS 3

__device__ __forceinline__ float wred_sum(float v){
  #pragma unroll
  for (int s = 32; s > 0; s >>= 1) v += __shfl_xor(v, s, 64);
  return v;
}
__device__ __forceinline__ unsigned short f2bf(float x){
  unsigned int u = __float_as_uint(x);
  unsigned int r = (u + 0x7FFFu + ((u >> 16) & 1u)) >> 16;
  return (unsigned short)r;
}
__device__ __forceinline__ float bf2f(unsigned short b){
  return __uint_as_float(((unsigned int)b) << 16);
}

// ---------------- GEMM: Cb[M,NC](bf16) = A[M,K](f32) @ B[K,NC](f32) ------
// 64x64 tile, 256 threads, 4x4 microtile, K-chunk 32, k-major A in LDS
__global__ __launch_bounds__(256) void gemm_kernel(
    const float* __restrict__ A, const float* __restrict__ B,
    unsigned short* __restrict__ Cb, int M, int K, int NC)
{
  __shared__ __align__(16) float a_s[32][68];
  __shared__ __align__(16) float b_s[32][68];
  const int tid  = threadIdx.x;
  const int row0 = blockIdx.x * 64;
  const int col0 = blockIdx.y * 64;
  const int tx = tid & 15, ty = tid >> 4;
  float acc[4][4] = {};

  for (int kc = 0; kc < K; kc += 32) {
    #pragma unroll
    for (int p = 0; p < 2; ++p) {
      int idx = tid + p * 256;
      int r = idx >> 3, kg = (idx & 7) << 2;
      float4 v = make_float4(0.f, 0.f, 0.f, 0.f);
      int gr = row0 + r;
      if (gr < M) v = *(const float4*)&A[(size_t)gr * K + kc + kg];
      a_s[kg + 0][r] = v.x; a_s[kg + 1][r] = v.y;
      a_s[kg + 2][r] = v.z; a_s[kg + 3][r] = v.w;
    }
    #pragma unroll
    for (int p = 0; p < 2; ++p) {
      int idx = tid + p * 256;
      int kr = idx >> 4, cg = (idx & 15) << 2;
      float4 v = make_float4(0.f, 0.f, 0.f, 0.f);
      if (col0 + cg + 3 < NC) v = *(const float4*)&B[(size_t)(kc + kr) * NC + col0 + cg];
      *(float4*)&b_s[kr][cg] = v;
    }
    __syncthreads();
    #pragma unroll
    for (int k = 0; k < 32; ++k) {
      float4 va4 = *(const float4*)&a_s[k][ty << 2];
      float4 vb4 = *(const float4*)&b_s[k][tx << 2];
      float av[4] = {va4.x, va4.y, va4.z, va4.w};
      float bv[4] = {vb4.x, vb4.y, vb4.z, vb4.w};
      #pragma unroll
      for (int i = 0; i < 4; ++i)
        #pragma unroll
        for (int j = 0; j < 4; ++j)
          acc[i][j] += av[i] * bv[j];
    }
    __syncthreads();
  }
  #pragma unroll
  for (int i = 0; i < 4; ++i) {
    int gr = row0 + (ty << 2) + i;
    if (gr < M && col0 + (tx << 2) + 3 < NC) {
      ushort4 v;
      v.x = f2bf(acc[i][0]); v.y = f2bf(acc[i][1]);
      v.z = f2bf(acc[i][2]); v.w = f2bf(acc[i][3]);
      *(ushort4*)&Cb[(size_t)gr * NC + col0 + (tx << 2)] = v;
    }
  }
}

// ---------------- el/er: one wave per (node, head), bf16 feat ----------------
__global__ __launch_bounds__(256) void attn_coef_kernel(
    const unsigned short* __restrict__ featb, const float* __restrict__ al,
    const float* __restrict__ ar, float* __restrict__ el, float* __restrict__ er,
    int N, int F)
{
  int wid  = blockIdx.x * 4 + (threadIdx.x >> 6);
  int lane = threadIdx.x & 63;
  if (wid >= N * HEADS) return;
  int n = wid / HEADS, h = wid - n * HEADS;
  float v = 0.f, a = 0.f, b = 0.f;
  if (lane < F) {
    v = bf2f(featb[(size_t)n * (HEADS * F) + h * F + lane]);
    a = al[h * F + lane];
    b = ar[h * F + lane];
  }
  float se = wred_sum(v * a);
  float sr = wred_sum(v * b);
  if (lane == 0) { el[n * HEADS + h] = se; er[n * HEADS + h] = sr; }
}

// ---------------- CSR build ----------------
__global__ __launch_bounds__(256) void count_deg_kernel(
    const int* __restrict__ dst, int* __restrict__ deg, int E)
{
  for (int i = blockIdx.x * blockDim.x + threadIdx.x; i < E; i += gridDim.x * blockDim.x)
    atomicAdd(&deg[dst[i]], 1);
}

__global__ __launch_bounds__(1024) void scan_kernel(
    const int* __restrict__ deg, int* __restrict__ off, int n)
{
  __shared__ int tmp[1024];
  __shared__ int carry;
  int t = threadIdx.x;
  if (t == 0) carry = 0;
  __syncthreads();
  for (int base = 0; base <= n; base += 1024) {
    int i = base + t;
    int v = (i < n) ? deg[i] : 0;
    tmp[t] = v;
    __syncthreads();
    for (int s = 1; s < 1024; s <<= 1) {
      int a = (t >= s) ? tmp[t - s] : 0;
      __syncthreads();
      tmp[t] += a;
      __syncthreads();
    }
    int incl = tmp[t];
    if (i <= n) off[i] = carry + incl - v;
    int ct = tmp[1023];
    __syncthreads();
    if (t == 0) carry += ct;
    __syncthreads();
  }
}

__global__ __launch_bounds__(256) void fill_adj_kernel(
    const int* __restrict__ src, const int* __restrict__ dst,
    const int* __restrict__ off, int* __restrict__ cur, int* __restrict__ adj, int E)
{
  for (int i = blockIdx.x * blockDim.x + threadIdx.x; i < E; i += gridDim.x * blockDim.x) {
    int dn = dst[i];
    int p  = atomicAdd(&cur[dn], 1);
    adj[off[dn] + p] = src[i];
  }
}

// ---------------- aggregation: one wave per destination node ----------------
// Fused online-softmax (max+sum in one pass) + weighted gather of bf16 feat.
// mode 0: F=64, out = relu(agg) stored [N,192] fp32
// mode 1: F=40, out = mean over heads stored [N,40] fp32
__global__ __launch_bounds__(256) void aggregate_kernel(
    const unsigned short* __restrict__ featb, const int* __restrict__ adj,
    const int* __restrict__ off, const float* __restrict__ el,
    const float* __restrict__ er, float* __restrict__ out,
    int N, int F, int mode)
{
  int n    = blockIdx.x * 4 + (threadIdx.x >> 6);
  int lane = threadIdx.x & 63;
  if (n >= N) return;
  const int NC = HEADS * F;
  int o0 = off[n];
  int d  = off[n + 1] - o0;
  float er0 = er[n * 3 + 0], er1 = er[n * 3 + 1], er2 = er[n * 3 + 2];

  // fused pass: per-lane online softmax (max + rescaled sum)
  float m0 = -1e30f, m1 = -1e30f, m2 = -1e30f;
  float s0 = 0.f, s1 = 0.f, s2 = 0.f;
  for (int i = lane; i < d; i += 64) {
    int s = adj[o0 + i];
    float x0 = el[s * 3 + 0] + er0; x0 = x0 > 0.f ? x0 : 0.2f * x0;
    float x1 = el[s * 3 + 1] + er1; x1 = x1 > 0.f ? x1 : 0.2f * x1;
    float x2 = el[s * 3 + 2] + er2; x2 = x2 > 0.f ? x2 : 0.2f * x2;
    float M0 = fmaxf(m0, x0), M1 = fmaxf(m1, x1), M2 = fmaxf(m2, x2);
    s0 = s0 * __expf(m0 - M0) + __expf(x0 - M0); m0 = M0;
    s1 = s1 * __expf(m1 - M1) + __expf(x1 - M1); m1 = M1;
    s2 = s2 * __expf(m2 - M2) + __expf(x2 - M2); m2 = M2;
  }
  // wave combine of (m, s) pairs
  #pragma unroll
  for (int o = 32; o > 0; o >>= 1) {
    float mo, so, M;
    mo = __shfl_xor(m0, o, 64); so = __shfl_xor(s0, o, 64);
    M = fmaxf(m0, mo); s0 = s0 * __expf(m0 - M) + so * __expf(mo - M); m0 = M;
    mo = __shfl_xor(m1, o, 64); so = __shfl_xor(s1, o, 64);
    M = fmaxf(m1, mo); s1 = s1 * __expf(m1 - M) + so * __expf(mo - M); m1 = M;
    mo = __shfl_xor(m2, o, 64); so = __shfl_xor(s2, o, 64);
    M = fmaxf(m2, mo); s2 = s2 * __expf(m2 - M) + so * __expf(mo - M); m2 = M;
  }
  float i0 = s0 > 0.f ? 1.f / s0 : 0.f;
  float i1 = s1 > 0.f ? 1.f / s1 : 0.f;
  float i2 = s2 > 0.f ? 1.f / s2 : 0.f;

  // weighted accumulation pass (bf16 gather)
  float a0 = 0.f, a1 = 0.f, a2 = 0.f;
  for (int base = 0; base < d; base += 64) {
    int i = base + lane;
    int ssrc = 0; float p0 = 0.f, p1 = 0.f, p2 = 0.f;
    if (i < d) {
      ssrc = adj[o0 + i];
      float x0 = el[ssrc * 3 + 0] + er0; x0 = x0 > 0.f ? x0 : 0.2f * x0;
      float x1 = el[ssrc * 3 + 1] + er1; x1 = x1 > 0.f ? x1 : 0.2f * x1;
      float x2 = el[ssrc * 3 + 2] + er2; x2 = x2 > 0.f ? x2 : 0.2f * x2;
      p0 = __expf(x0 - m0) * i0;
      p1 = __expf(x1 - m1) * i1;
      p2 = __expf(x2 - m2) * i2;
    }
    int cnt = min(64, d - base);
    for (int e = 0; e < cnt; ++e) {
      int   se = __shfl(ssrc, e, 64);
      float w0 = __shfl(p0, e, 64);
      float w1 = __shfl(p1, e, 64);
      float w2 = __shfl(p2, e, 64);
      const unsigned short* fr = featb + (size_t)se * NC;
      if (F == 64) {
        a0 += w0 * bf2f(fr[lane]);
        a1 += w1 * bf2f(fr[64 + lane]);
        a2 += w2 * bf2f(fr[128 + lane]);
      } else { // F == 40, NC = 120; lane holds elems {lane, 64+lane}
        float wa = lane < 40 ? w0 : w1;
        a0 += wa * bf2f(fr[lane]);
        if (lane < 56) {
          float wb = lane < 16 ? w1 : w2;
          a1 += wb * bf2f(fr[64 + lane]);
        }
      }
    }
  }

  if (mode == 0) {
    out[(size_t)n * 192 + lane]       = fmaxf(a0, 0.f);
    out[(size_t)n * 192 + 64 + lane]  = fmaxf(a1, 0.f);
    out[(size_t)n * 192 + 128 + lane] = fmaxf(a2, 0.f);
  } else {
    // combine heads: out[f] = (elem f + elem f+40 + elem f+80) / 3
    float t1 = __shfl(a0, lane + 40, 64);  // valid for lane < 24
    float t2 = __shfl(a1, lane - 24, 64);  // valid for lane >= 24
    float e2 = (lane < 24) ? t1 : t2;
    float e3 = __shfl(a1, lane + 16, 64);  // elem lane+80
    if (lane < 40) out[(size_t)n * 40 + lane] = (a0 + e2 + e3) * (1.0f / 3.0f);
  }
}

extern "C" void kernel_launch(void* const* d_in, const int* in_sizes, int n_in,
                              void* d_out, int out_size, void* d_ws, size_t ws_size,
                              hipStream_t stream) {
  const float* x   = (const float*)d_in[0];
  const int*   src = (const int*)d_in[1];
  const int*   dst = (const int*)d_in[2];
  const float* W0  = (const float*)d_in[3];
  const float* al0 = (const float*)d_in[4];
  const float* ar0 = (const float*)d_in[5];
  const float* W1  = (const float*)d_in[6];
  const float* al1 = (const float*)d_in[7];
  const float* ar1 = (const float*)d_in[8];
  const float* W2  = (const float*)d_in[9];
  const float* al2 = (const float*)d_in[10];
  const float* ar2 = (const float*)d_in[11];
  const int N = NNODES;
  const int E = in_sizes[1];
  float* out = (float*)d_out;

  char* w = (char*)d_ws;
  float*          bufA  = (float*)w;          w += (size_t)N * 192 * 4;  // agg out (fp32)
  unsigned short* featb = (unsigned short*)w; w += (size_t)N * 192 * 2;  // bf16 feat
  float* el   = (float*)w; w += (size_t)N * 3 * 4;
  float* er   = (float*)w; w += (size_t)N * 3 * 4;
  int* deg = (int*)w; w += (size_t)N * 4;
  int* off = (int*)w; w += (size_t)(N + 1) * 4;
  int* cur = (int*)w; w += (size_t)N * 4;
  int* adj = (int*)w; w += (size_t)E * 4;

  // CSR build (graph static across layers)
  hipMemsetAsync(deg, 0, (size_t)N * 4, stream);
  hipMemsetAsync(cur, 0, (size_t)N * 4, stream);
  count_deg_kernel<<<2048, 256, 0, stream>>>(dst, deg, E);
  scan_kernel<<<1, 1024, 0, stream>>>(deg, off, N);
  fill_adj_kernel<<<2048, 256, 0, stream>>>(src, dst, off, cur, adj, E);

  dim3 g01((N + 63) / 64, 3);
  dim3 g2((N + 63) / 64, 2);
  int cblk = (N * 3 + 3) / 4;
  int ablk = (N + 3) / 4;

  // layer 0
  gemm_kernel<<<g01, 256, 0, stream>>>(x, W0, featb, N, 256, 192);
  attn_coef_kernel<<<cblk, 256, 0, stream>>>(featb, al0, ar0, el, er, N, 64);
  aggregate_kernel<<<ablk, 256, 0, stream>>>(featb, adj, off, el, er, bufA, N, 64, 0);
  // layer 1
  gemm_kernel<<<g01, 256, 0, stream>>>(bufA, W1, featb, N, 192, 192);
  attn_coef_kernel<<<cblk, 256, 0, stream>>>(featb, al1, ar1, el, er, N, 64);
  aggregate_kernel<<<ablk, 256, 0, stream>>>(featb, adj, off, el, er, bufA, N, 64, 0);
  // layer 2
  gemm_kernel<<<g2, 256, 0, stream>>>(bufA, W2, featb, N, 192, 120);
  attn_coef_kernel<<<cblk, 256, 0, stream>>>(featb, al2, ar2, el, er, N, 40);
  aggregate_kernel<<<ablk, 256, 0, stream>>>(featb, adj, off, el, er, out, N, 40, 1);
}

// Round 3
// 719.694 us; speedup vs baseline: 1.3674x; 1.2416x over previous
//
#include <hip/hip_runtime.h>

#define NNODES 50000
#define HEADS 3

typedef __attribute__((ext_vector_type(8))) short bf16x8;
typedef __attribute__((ext_vector_type(4))) float f32x4;

__device__ __forceinline__ float wred_sum(float v){
  #pragma unroll
  for (int s = 32; s > 0; s >>= 1) v += __shfl_xor(v, s, 64);
  return v;
}
__device__ __forceinline__ unsigned short f2bf(float x){
  unsigned int u = __float_as_uint(x);
  unsigned int r = (u + 0x7FFFu + ((u >> 16) & 1u)) >> 16;
  return (unsigned short)r;
}
__device__ __forceinline__ float bf2f(unsigned short b){
  return __uint_as_float(((unsigned int)b) << 16);
}

// ---------------- x (fp32) -> bf16, vectorized ----------------
__global__ __launch_bounds__(256) void cvt_bf16_kernel(
    const float* __restrict__ in, unsigned short* __restrict__ outb, int n4)
{
  int i = blockIdx.x * 256 + threadIdx.x;
  if (i >= n4) return;
  float4 v = ((const float4*)in)[i];
  ushort4 o;
  o.x = f2bf(v.x); o.y = f2bf(v.y); o.z = f2bf(v.z); o.w = f2bf(v.w);
  ((ushort4*)outb)[i] = o;
}

// ---------------- W [K][NCv] fp32 -> MFMA-fragment-ordered bf16 ----------------
// layout: frag (kc, t, lane) holds 8 bf16: B[kc*32 + 8*(lane>>4) + j][t*16 + (lane&15)]
__global__ __launch_bounds__(256) void prep_b_kernel(
    const float* __restrict__ B, unsigned short* __restrict__ Bf,
    int K, int NT, int NCv)
{
  int tid = blockIdx.x * 256 + threadIdx.x;
  int total = (K >> 5) * NT * 64;
  if (tid >= total) return;
  int l  = tid & 63;
  int t  = (tid >> 6) % NT;
  int kc = tid / (NT * 64);
  int k0  = kc * 32 + (l >> 4) * 8;
  int col = t * 16 + (l & 15);
  unsigned short o[8];
  #pragma unroll
  for (int j = 0; j < 8; ++j) {
    float v = (col < NCv) ? B[(size_t)(k0 + j) * NCv + col] : 0.f;
    o[j] = f2bf(v);
  }
  ushort4* dst = (ushort4*)&Bf[(size_t)tid * 8];
  dst[0] = make_ushort4(o[0], o[1], o[2], o[3]);
  dst[1] = make_ushort4(o[4], o[5], o[6], o[7]);
}

// ---------------- MFMA GEMM: Cb[M,NCv](bf16) = Ab[M,K](bf16) @ Worig ------
// 256 thr = 4 waves; wave w: rows blk*64..+63, cols w*NTW*16..; no LDS.
template<int NTW>
__global__ __launch_bounds__(256) void gemm_mfma_kernel(
    const unsigned short* __restrict__ Ab, const unsigned short* __restrict__ Bf,
    unsigned short* __restrict__ Cb, int M, int K, int NT, int NCv)
{
  const int w = threadIdx.x >> 6, l = threadIdx.x & 63;
  const int lrow = l & 15, kg = l >> 4;
  const int r0 = blockIdx.x * 64;
  const bf16x8* Bfv = (const bf16x8*)Bf;

  f32x4 acc[4][NTW];
  #pragma unroll
  for (int mt = 0; mt < 4; ++mt)
    #pragma unroll
    for (int t = 0; t < NTW; ++t)
      acc[mt][t] = (f32x4){0.f, 0.f, 0.f, 0.f};

  const int nkc = K >> 5;
  for (int kc = 0; kc < nkc; ++kc) {
    bf16x8 af[4];
    #pragma unroll
    for (int mt = 0; mt < 4; ++mt) {
      int row = r0 + mt * 16 + lrow;
      bf16x8 z = {0,0,0,0,0,0,0,0};
      af[mt] = z;
      if (row < M)
        af[mt] = *(const bf16x8*)&Ab[(size_t)row * K + kc * 32 + kg * 8];
    }
    #pragma unroll
    for (int t = 0; t < NTW; ++t) {
      bf16x8 bfr = Bfv[((size_t)kc * NT + w * NTW + t) * 64 + l];
      #pragma unroll
      for (int mt = 0; mt < 4; ++mt)
        acc[mt][t] = __builtin_amdgcn_mfma_f32_16x16x32_bf16(af[mt], bfr, acc[mt][t], 0, 0, 0);
    }
  }
  #pragma unroll
  for (int mt = 0; mt < 4; ++mt)
    #pragma unroll
    for (int t = 0; t < NTW; ++t) {
      int col = (w * NTW + t) * 16 + lrow;
      #pragma unroll
      for (int rr = 0; rr < 4; ++rr) {
        int row = r0 + mt * 16 + kg * 4 + rr;
        if (row < M && col < NCv)
          Cb[(size_t)row * NCv + col] = f2bf(acc[mt][t][rr]);
      }
    }
}

// ---------------- el/er: one wave per (node, head), bf16 feat ----------------
// elp/erp stored stride-4 (float4 rows) for single-load gathers downstream.
__global__ __launch_bounds__(256) void attn_coef_kernel(
    const unsigned short* __restrict__ featb, const float* __restrict__ al,
    const float* __restrict__ ar, float* __restrict__ elp, float* __restrict__ erp,
    int N, int F)
{
  int wid  = blockIdx.x * 4 + (threadIdx.x >> 6);
  int lane = threadIdx.x & 63;
  if (wid >= N * HEADS) return;
  int n = wid / HEADS, h = wid - n * HEADS;
  float v = 0.f, a = 0.f, b = 0.f;
  if (lane < F) {
    v = bf2f(featb[(size_t)n * (HEADS * F) + h * F + lane]);
    a = al[h * F + lane];
    b = ar[h * F + lane];
  }
  float se = wred_sum(v * a);
  float sr = wred_sum(v * b);
  if (lane == 0) { elp[n * 4 + h] = se; erp[n * 4 + h] = sr; }
}

// ---------------- CSR build ----------------
__global__ __launch_bounds__(256) void count_deg_kernel(
    const int* __restrict__ dst, int* __restrict__ deg, int E)
{
  for (int i = blockIdx.x * blockDim.x + threadIdx.x; i < E; i += gridDim.x * blockDim.x)
    atomicAdd(&deg[dst[i]], 1);
}

__global__ __launch_bounds__(1024) void scan_kernel(
    const int* __restrict__ deg, int* __restrict__ off, int n)
{
  __shared__ int wsum[16];
  __shared__ int carry;
  int t = threadIdx.x, wv = t >> 6, l = t & 63;
  if (t == 0) carry = 0;
  __syncthreads();
  for (int base = 0; base <= n; base += 1024) {
    int i = base + t;
    int v = (i < n) ? deg[i] : 0;
    int x = v;
    #pragma unroll
    for (int s = 1; s < 64; s <<= 1) {
      int y = __shfl_up(x, s, 64);
      if (l >= s) x += y;
    }
    if (l == 63) wsum[wv] = x;
    __syncthreads();
    int woff = 0, tot = 0;
    #pragma unroll
    for (int k = 0; k < 16; ++k) {
      int wk = wsum[k];
      woff += (k < wv) ? wk : 0;
      tot  += wk;
    }
    int c = carry;
    if (i <= n) off[i] = c + woff + x - v;
    __syncthreads();
    if (t == 0) carry = c + tot;
    __syncthreads();
  }
}

__global__ __launch_bounds__(256) void fill_adj_kernel(
    const int* __restrict__ src, const int* __restrict__ dst,
    const int* __restrict__ off, int* __restrict__ cur, int* __restrict__ adj, int E)
{
  for (int i = blockIdx.x * blockDim.x + threadIdx.x; i < E; i += gridDim.x * blockDim.x) {
    int dn = dst[i];
    int p  = atomicAdd(&cur[dn], 1);
    adj[off[dn] + p] = src[i];
  }
}

// ---------------- aggregation: one wave per destination node ----------------
// mode 0: F=64, out = relu(agg) -> bf16 [N,192]
// mode 1: F=40, out = mean over heads -> fp32 [N,40]
__global__ __launch_bounds__(256) void aggregate_kernel(
    const unsigned short* __restrict__ featb, const int* __restrict__ adj,
    const int* __restrict__ off, const float* __restrict__ elp,
    const float* __restrict__ erp, void* __restrict__ outp,
    int N, int F, int mode)
{
  __shared__ float pl[4][208];
  int wv   = threadIdx.x >> 6;
  int n    = blockIdx.x * 4 + wv;
  int l    = threadIdx.x & 63;
  if (n >= N) return;
  const int NC = HEADS * F;
  int o0 = off[n];
  int d  = off[n + 1] - o0;
  float er0 = erp[n * 4 + 0], er1 = erp[n * 4 + 1], er2 = erp[n * 4 + 2];
  const float4* elv = (const float4*)elp;

  // fused online softmax pass (max + rescaled sum)
  float m0 = -1e30f, m1 = -1e30f, m2 = -1e30f;
  float s0 = 0.f, s1 = 0.f, s2 = 0.f;
  for (int i = l; i < d; i += 64) {
    int s = adj[o0 + i];
    float4 ev = elv[s];
    float x0 = ev.x + er0; x0 = x0 > 0.f ? x0 : 0.2f * x0;
    float x1 = ev.y + er1; x1 = x1 > 0.f ? x1 : 0.2f * x1;
    float x2 = ev.z + er2; x2 = x2 > 0.f ? x2 : 0.2f * x2;
    float M0 = fmaxf(m0, x0), M1 = fmaxf(m1, x1), M2 = fmaxf(m2, x2);
    s0 = s0 * __expf(m0 - M0) + __expf(x0 - M0); m0 = M0;
    s1 = s1 * __expf(m1 - M1) + __expf(x1 - M1); m1 = M1;
    s2 = s2 * __expf(m2 - M2) + __expf(x2 - M2); m2 = M2;
  }
  #pragma unroll
  for (int o = 32; o > 0; o >>= 1) {
    float mo, so, M;
    mo = __shfl_xor(m0, o, 64); so = __shfl_xor(s0, o, 64);
    M = fmaxf(m0, mo); s0 = s0 * __expf(m0 - M) + so * __expf(mo - M); m0 = M;
    mo = __shfl_xor(m1, o, 64); so = __shfl_xor(s1, o, 64);
    M = fmaxf(m1, mo); s1 = s1 * __expf(m1 - M) + so * __expf(mo - M); m1 = M;
    mo = __shfl_xor(m2, o, 64); so = __shfl_xor(s2, o, 64);
    M = fmaxf(m2, mo); s2 = s2 * __expf(m2 - M) + so * __expf(mo - M); m2 = M;
  }
  float i0 = s0 > 0.f ? 1.f / s0 : 0.f;
  float i1 = s1 > 0.f ? 1.f / s1 : 0.f;
  float i2 = s2 > 0.f ? 1.f / s2 : 0.f;

  // weighted gather: 1 uint2 load per edge per lane (lanes < gl)
  const int gl = (F == 64) ? 48 : 30;     // active gather lanes (4 feats each)
  const int h  = (F == 64) ? (l >> 4) : (l / 10);
  float4 acc = {0.f, 0.f, 0.f, 0.f};
  for (int base = 0; base < d; base += 64) {
    int i = base + l;
    int ssrc = 0; float p0 = 0.f, p1 = 0.f, p2 = 0.f;
    if (i < d) {
      ssrc = adj[o0 + i];
      float4 ev = elv[ssrc];
      float x0 = ev.x + er0; x0 = x0 > 0.f ? x0 : 0.2f * x0;
      float x1 = ev.y + er1; x1 = x1 > 0.f ? x1 : 0.2f * x1;
      float x2 = ev.z + er2; x2 = x2 > 0.f ? x2 : 0.2f * x2;
      p0 = __expf(x0 - m0) * i0;
      p1 = __expf(x1 - m1) * i1;
      p2 = __expf(x2 - m2) * i2;
    }
    pl[wv][l]       = p0;
    pl[wv][65 + l]  = p1;
    pl[wv][130 + l] = p2;
    int cnt = min(64, d - base);
    for (int e = 0; e < cnt; ++e) {
      int se = __shfl(ssrc, e, 64);
      if (l < gl) {
        uint2 u = ((const uint2*)(featb + (size_t)se * NC))[l];
        float w = pl[wv][h * 65 + e];
        acc.x += w * __uint_as_float(u.x << 16);
        acc.y += w * __uint_as_float(u.x & 0xffff0000u);
        acc.z += w * __uint_as_float(u.y << 16);
        acc.w += w * __uint_as_float(u.y & 0xffff0000u);
      }
    }
  }

  if (mode == 0) {
    if (l < 48) {
      ushort4 o;
      o.x = f2bf(fmaxf(acc.x, 0.f)); o.y = f2bf(fmaxf(acc.y, 0.f));
      o.z = f2bf(fmaxf(acc.z, 0.f)); o.w = f2bf(fmaxf(acc.w, 0.f));
      *(ushort4*)((unsigned short*)outp + (size_t)n * 192 + l * 4) = o;
    }
  } else {
    // mean over heads: lane f/4 (h0) + lane+10 (h1) + lane+20 (h2), same component
    float bx = __shfl(acc.x, l + 10, 64), cx = __shfl(acc.x, l + 20, 64);
    float by = __shfl(acc.y, l + 10, 64), cy = __shfl(acc.y, l + 20, 64);
    float bz = __shfl(acc.z, l + 10, 64), cz = __shfl(acc.z, l + 20, 64);
    float bw = __shfl(acc.w, l + 10, 64), cw = __shfl(acc.w, l + 20, 64);
    if (l < 10) {
      float4 o;
      o.x = (acc.x + bx + cx) * (1.f / 3.f);
      o.y = (acc.y + by + cy) * (1.f / 3.f);
      o.z = (acc.z + bz + cz) * (1.f / 3.f);
      o.w = (acc.w + bw + cw) * (1.f / 3.f);
      *(float4*)((float*)outp + (size_t)n * 40 + l * 4) = o;
    }
  }
}

extern "C" void kernel_launch(void* const* d_in, const int* in_sizes, int n_in,
                              void* d_out, int out_size, void* d_ws, size_t ws_size,
                              hipStream_t stream) {
  const float* x   = (const float*)d_in[0];
  const int*   src = (const int*)d_in[1];
  const int*   dst = (const int*)d_in[2];
  const float* W0  = (const float*)d_in[3];
  const float* al0 = (const float*)d_in[4];
  const float* ar0 = (const float*)d_in[5];
  const float* W1  = (const float*)d_in[6];
  const float* al1 = (const float*)d_in[7];
  const float* ar1 = (const float*)d_in[8];
  const float* W2  = (const float*)d_in[9];
  const float* al2 = (const float*)d_in[10];
  const float* ar2 = (const float*)d_in[11];
  const int N = NNODES;
  const int E = in_sizes[1];
  float* out = (float*)d_out;

  char* w = (char*)d_ws;
  unsigned short* xb    = (unsigned short*)w; w += (size_t)N * 256 * 2;  // 25.6MB
  unsigned short* featb = (unsigned short*)w; w += (size_t)N * 192 * 2;  // 19.2MB
  unsigned short* aggb  = (unsigned short*)w; w += (size_t)N * 192 * 2;  // 19.2MB
  unsigned short* Bf    = (unsigned short*)w; w += (size_t)128 * 1024;   // 96KB+pad
  float* elp = (float*)w; w += (size_t)N * 4 * 4;
  float* erp = (float*)w; w += (size_t)N * 4 * 4;
  int* deg = (int*)w; w += (size_t)N * 4;
  int* off = (int*)w; w += (size_t)(N + 1) * 4;
  int* cur = (int*)w; w += (size_t)N * 4;
  int* adj = (int*)w; w += (size_t)E * 4;

  // x -> bf16
  cvt_bf16_kernel<<<(N * 256 / 4 + 255) / 256, 256, 0, stream>>>(x, xb, N * 256 / 4);

  // CSR build (graph static across layers)
  hipMemsetAsync(deg, 0, (size_t)N * 4, stream);
  hipMemsetAsync(cur, 0, (size_t)N * 4, stream);
  count_deg_kernel<<<2048, 256, 0, stream>>>(dst, deg, E);
  scan_kernel<<<1, 1024, 0, stream>>>(deg, off, N);
  fill_adj_kernel<<<2048, 256, 0, stream>>>(src, dst, off, cur, adj, E);

  int gblk = (N + 63) / 64;           // 782
  int cblk = (N * 3 + 3) / 4;
  int ablk = (N + 3) / 4;

  // layer 0: K=256, NT=12, NCv=192
  prep_b_kernel<<<(8 * 12 * 64 + 255) / 256, 256, 0, stream>>>(W0, Bf, 256, 12, 192);
  gemm_mfma_kernel<3><<<gblk, 256, 0, stream>>>(xb, Bf, featb, N, 256, 12, 192);
  attn_coef_kernel<<<cblk, 256, 0, stream>>>(featb, al0, ar0, elp, erp, N, 64);
  aggregate_kernel<<<ablk, 256, 0, stream>>>(featb, adj, off, elp, erp, aggb, N, 64, 0);
  // layer 1: K=192, NT=12, NCv=192
  prep_b_kernel<<<(6 * 12 * 64 + 255) / 256, 256, 0, stream>>>(W1, Bf, 192, 12, 192);
  gemm_mfma_kernel<3><<<gblk, 256, 0, stream>>>(aggb, Bf, featb, N, 192, 12, 192);
  attn_coef_kernel<<<cblk, 256, 0, stream>>>(featb, al1, ar1, elp, erp, N, 64);
  aggregate_kernel<<<ablk, 256, 0, stream>>>(featb, adj, off, elp, erp, aggb, N, 64, 0);
  // layer 2: K=192, NT=8 (pad 120->128), NCv=120
  prep_b_kernel<<<(6 * 8 * 64 + 255) / 256, 256, 0, stream>>>(W2, Bf, 192, 8, 120);
  gemm_mfma_kernel<2><<<gblk, 256, 0, stream>>>(aggb, Bf, featb, N, 192, 8, 120);
  attn_coef_kernel<<<cblk, 256, 0, stream>>>(featb, al2, ar2, elp, erp, N, 40);
  aggregate_kernel<<<ablk, 256, 0, stream>>>(featb, adj, off, elp, erp, out, N, 40, 1);
}

// Round 4
// 664.993 us; speedup vs baseline: 1.4798x; 1.0823x over previous
//
#include <hip/hip_runtime.h>

#define NNODES 50000
#define HEADS 3

typedef __attribute__((ext_vector_type(8))) short bf16x8;
typedef __attribute__((ext_vector_type(4))) float f32x4;

__device__ __forceinline__ float wred_sum(float v){
  #pragma unroll
  for (int s = 32; s > 0; s >>= 1) v += __shfl_xor(v, s, 64);
  return v;
}
__device__ __forceinline__ unsigned short f2bf(float x){
  unsigned int u = __float_as_uint(x);
  unsigned int r = (u + 0x7FFFu + ((u >> 16) & 1u)) >> 16;
  return (unsigned short)r;
}

// ---------------- x (fp32) -> bf16, vectorized ----------------
__global__ __launch_bounds__(256) void cvt_bf16_kernel(
    const float* __restrict__ in, unsigned short* __restrict__ outb, int n4)
{
  int i = blockIdx.x * 256 + threadIdx.x;
  if (i >= n4) return;
  float4 v = ((const float4*)in)[i];
  ushort4 o;
  o.x = f2bf(v.x); o.y = f2bf(v.y); o.z = f2bf(v.z); o.w = f2bf(v.w);
  ((ushort4*)outb)[i] = o;
}

// ---------------- W -> MFMA-fragment bf16, with folded el/er columns -------
// Virtual B matrix Bx[K][NT*16]:
//   c < NCf            : W[k][c]
//   c in [NCf, NCf+3)  : wl[k][c-NCf]   = sum_f W[k][h*F+f] * al[h][f]
//   c in [NCf+3,NCf+6) : wr[k][c-NCf-3] = sum_f W[k][h*F+f] * ar[h][f]
//   else 0
// frag (kc,t,lane) holds 8 bf16: Bx[kc*32 + 8*(lane>>4) + j][t*16 + (lane&15)]
__global__ __launch_bounds__(256) void prep_b_kernel(
    const float* __restrict__ W, const float* __restrict__ al,
    const float* __restrict__ ar, unsigned short* __restrict__ Bf,
    int K, int NT, int NCf, int F)
{
  int tid = blockIdx.x * 256 + threadIdx.x;
  int total = (K >> 5) * NT * 64;
  if (tid >= total) return;
  int l  = tid & 63;
  int t  = (tid >> 6) % NT;
  int kc = tid / (NT * 64);
  int k0  = kc * 32 + (l >> 4) * 8;
  int col = t * 16 + (l & 15);
  unsigned short o[8];
  #pragma unroll
  for (int j = 0; j < 8; ++j) {
    int k = k0 + j;
    float v = 0.f;
    if (col < NCf) {
      v = W[(size_t)k * NCf + col];
    } else if (col < NCf + 6) {
      int c = col - NCf;
      int h = (c < 3) ? c : c - 3;
      const float* av = ((c < 3) ? al : ar) + h * F;
      const float* wp = W + (size_t)k * NCf + h * F;
      float a = 0.f;
      for (int f = 0; f < F; ++f) a += wp[f] * av[f];
      v = a;
    }
    o[j] = f2bf(v);
  }
  ushort4* dst = (ushort4*)&Bf[(size_t)tid * 8];
  dst[0] = make_ushort4(o[0], o[1], o[2], o[3]);
  dst[1] = make_ushort4(o[4], o[5], o[6], o[7]);
}

// ---------------- MFMA GEMM + el/er epilogue ----------------
// 4 waves; wave w handles tiles {w, w+4, w+8, w+12} (< NT). 64 rows/block.
__global__ __launch_bounds__(256) void gemm_mfma_kernel(
    const unsigned short* __restrict__ Ab, const unsigned short* __restrict__ Bf,
    unsigned short* __restrict__ Cb, float* __restrict__ elp, float* __restrict__ erp,
    int M, int K, int NT, int NCf)
{
  const int w = threadIdx.x >> 6, l = threadIdx.x & 63;
  const int lrow = l & 15, kg = l >> 4;
  const int r0 = blockIdx.x * 64;
  const bf16x8* Bfv = (const bf16x8*)Bf;

  f32x4 acc[4][4];
  #pragma unroll
  for (int mt = 0; mt < 4; ++mt)
    #pragma unroll
    for (int j = 0; j < 4; ++j)
      acc[mt][j] = (f32x4){0.f, 0.f, 0.f, 0.f};

  const int nkc = K >> 5;
  for (int kc = 0; kc < nkc; ++kc) {
    bf16x8 af[4];
    #pragma unroll
    for (int mt = 0; mt < 4; ++mt) {
      int row = r0 + mt * 16 + lrow;
      bf16x8 z = {0,0,0,0,0,0,0,0};
      af[mt] = z;
      if (row < M)
        af[mt] = *(const bf16x8*)&Ab[(size_t)row * K + kc * 32 + kg * 8];
    }
    #pragma unroll
    for (int j = 0; j < 4; ++j) {
      int tile = w + 4 * j;
      if (tile < NT) {
        bf16x8 bfr = Bfv[((size_t)kc * NT + tile) * 64 + l];
        #pragma unroll
        for (int mt = 0; mt < 4; ++mt)
          acc[mt][j] = __builtin_amdgcn_mfma_f32_16x16x32_bf16(af[mt], bfr, acc[mt][j], 0, 0, 0);
      }
    }
  }
  #pragma unroll
  for (int j = 0; j < 4; ++j) {
    int tile = w + 4 * j;
    if (tile >= NT) continue;
    int c = tile * 16 + lrow;
    #pragma unroll
    for (int mt = 0; mt < 4; ++mt) {
      #pragma unroll
      for (int rr = 0; rr < 4; ++rr) {
        int row = r0 + mt * 16 + kg * 4 + rr;
        if (row >= M) continue;
        float v = acc[mt][j][rr];
        if (c < NCf)            Cb[(size_t)row * NCf + c] = f2bf(v);
        else if (c < NCf + 3)   elp[row * 4 + (c - NCf)] = v;
        else if (c < NCf + 6)   erp[row * 4 + (c - NCf - 3)] = v;
      }
    }
  }
}

// ---------------- CSR build ----------------
__global__ __launch_bounds__(256) void count_deg_kernel(
    const int* __restrict__ dst, int* __restrict__ deg, int E)
{
  for (int i = blockIdx.x * blockDim.x + threadIdx.x; i < E; i += gridDim.x * blockDim.x)
    atomicAdd(&deg[dst[i]], 1);
}

__global__ __launch_bounds__(1024) void scan_kernel(
    const int* __restrict__ deg, int* __restrict__ off, int n)
{
  __shared__ int wsum[16];
  __shared__ int carry;
  int t = threadIdx.x, wv = t >> 6, l = t & 63;
  if (t == 0) carry = 0;
  __syncthreads();
  for (int base = 0; base <= n; base += 1024) {
    int i = base + t;
    int v = (i < n) ? deg[i] : 0;
    int x = v;
    #pragma unroll
    for (int s = 1; s < 64; s <<= 1) {
      int y = __shfl_up(x, s, 64);
      if (l >= s) x += y;
    }
    if (l == 63) wsum[wv] = x;
    __syncthreads();
    int woff = 0, tot = 0;
    #pragma unroll
    for (int k = 0; k < 16; ++k) {
      int wk = wsum[k];
      woff += (k < wv) ? wk : 0;
      tot  += wk;
    }
    int c = carry;
    if (i <= n) off[i] = c + woff + x - v;
    __syncthreads();
    if (t == 0) carry = c + tot;
    __syncthreads();
  }
}

__global__ __launch_bounds__(256) void fill_adj_kernel(
    const int* __restrict__ src, const int* __restrict__ dst,
    const int* __restrict__ off, int* __restrict__ cur, int* __restrict__ adj, int E)
{
  for (int i = blockIdx.x * blockDim.x + threadIdx.x; i < E; i += gridDim.x * blockDim.x) {
    int dn = dst[i];
    int p  = atomicAdd(&cur[dn], 1);
    adj[off[dn] + p] = src[i];
  }
}

// ---------------- aggregation: one wave per dst node, flash-style ----------
// mode 0: F=64, out = relu(agg) -> bf16 [N,192]
// mode 1: F=40, out = mean over heads -> fp32 [N,40]
__global__ __launch_bounds__(256) void aggregate_kernel(
    const unsigned short* __restrict__ featb, const int* __restrict__ adj,
    const int* __restrict__ off, const float* __restrict__ elp,
    const float* __restrict__ erp, void* __restrict__ outp,
    int N, int F, int mode)
{
  __shared__ float4 pl[4][64];
  int wv = threadIdx.x >> 6, l = threadIdx.x & 63;
  int n  = blockIdx.x * 4 + wv;
  if (n >= N) return;
  const int NC = HEADS * F;
  const unsigned rowbytes = NC * 2;
  int o0 = off[n], d = off[n + 1] - o0;
  float er0 = erp[n * 4 + 0], er1 = erp[n * 4 + 1], er2 = erp[n * 4 + 2];
  const float4* elv = (const float4*)elp;
  const char* fbase = (const char*)featb;
  const int gl = (F == 64) ? 48 : 30;
  const int h  = (F == 64) ? (l >> 4) : (l / 10);
  const unsigned loff = (unsigned)l * 8u;
  const float4* plw = pl[wv];

  float m0 = -1e30f, m1 = -1e30f, m2 = -1e30f;
  float s0 = 0.f, s1 = 0.f, s2 = 0.f;
  float4 acc = {0.f, 0.f, 0.f, 0.f};

  for (int base = 0; base < d; base += 64) {
    int i = base + l;
    float x0 = -1e30f, x1 = -1e30f, x2 = -1e30f;
    unsigned boff = 0;
    if (i < d) {
      int ssrc = adj[o0 + i];
      boff = (unsigned)ssrc * rowbytes;
      float4 ev = elv[ssrc];
      x0 = ev.x + er0; x0 = fmaxf(x0, 0.2f * x0);
      x1 = ev.y + er1; x1 = fmaxf(x1, 0.2f * x1);
      x2 = ev.z + er2; x2 = fmaxf(x2, 0.2f * x2);
    }
    // chunk max per head
    float c0 = x0, c1 = x1, c2 = x2;
    #pragma unroll
    for (int o_ = 32; o_ > 0; o_ >>= 1) {
      c0 = fmaxf(c0, __shfl_xor(c0, o_, 64));
      c1 = fmaxf(c1, __shfl_xor(c1, o_, 64));
      c2 = fmaxf(c2, __shfl_xor(c2, o_, 64));
    }
    float M0 = fmaxf(m0, c0), M1 = fmaxf(m1, c1), M2 = fmaxf(m2, c2);
    float r0 = __expf(m0 - M0), r1 = __expf(m1 - M1), r2 = __expf(m2 - M2);
    s0 *= r0; s1 *= r1; s2 *= r2;
    float rh = (h == 0) ? r0 : (h == 1) ? r1 : r2;
    acc.x *= rh; acc.y *= rh; acc.z *= rh; acc.w *= rh;
    m0 = M0; m1 = M1; m2 = M2;
    float p0 = __expf(x0 - M0), p1 = __expf(x1 - M1), p2 = __expf(x2 - M2);
    s0 += p0; s1 += p1; s2 += p2;
    pl[wv][l] = make_float4(__uint_as_float(boff), p0, p1, p2);

    int cnt = min(64, d - base);
    if (l < gl) {
      int e = 0;
      for (; e + 4 <= cnt; e += 4) {
        float4 a0 = plw[e], a1 = plw[e + 1], a2 = plw[e + 2], a3 = plw[e + 3];
        uint2 u0 = *(const uint2*)(fbase + (__float_as_uint(a0.x) + loff));
        uint2 u1 = *(const uint2*)(fbase + (__float_as_uint(a1.x) + loff));
        uint2 u2 = *(const uint2*)(fbase + (__float_as_uint(a2.x) + loff));
        uint2 u3 = *(const uint2*)(fbase + (__float_as_uint(a3.x) + loff));
        float w0 = (h == 0) ? a0.y : (h == 1) ? a0.z : a0.w;
        float w1 = (h == 0) ? a1.y : (h == 1) ? a1.z : a1.w;
        float w2 = (h == 0) ? a2.y : (h == 1) ? a2.z : a2.w;
        float w3 = (h == 0) ? a3.y : (h == 1) ? a3.z : a3.w;
        acc.x += w0 * __uint_as_float(u0.x << 16);
        acc.y += w0 * __uint_as_float(u0.x & 0xffff0000u);
        acc.z += w0 * __uint_as_float(u0.y << 16);
        acc.w += w0 * __uint_as_float(u0.y & 0xffff0000u);
        acc.x += w1 * __uint_as_float(u1.x << 16);
        acc.y += w1 * __uint_as_float(u1.x & 0xffff0000u);
        acc.z += w1 * __uint_as_float(u1.y << 16);
        acc.w += w1 * __uint_as_float(u1.y & 0xffff0000u);
        acc.x += w2 * __uint_as_float(u2.x << 16);
        acc.y += w2 * __uint_as_float(u2.x & 0xffff0000u);
        acc.z += w2 * __uint_as_float(u2.y << 16);
        acc.w += w2 * __uint_as_float(u2.y & 0xffff0000u);
        acc.x += w3 * __uint_as_float(u3.x << 16);
        acc.y += w3 * __uint_as_float(u3.x & 0xffff0000u);
        acc.z += w3 * __uint_as_float(u3.y << 16);
        acc.w += w3 * __uint_as_float(u3.y & 0xffff0000u);
      }
      for (; e < cnt; ++e) {
        float4 a0 = plw[e];
        uint2 u0 = *(const uint2*)(fbase + (__float_as_uint(a0.x) + loff));
        float w0 = (h == 0) ? a0.y : (h == 1) ? a0.z : a0.w;
        acc.x += w0 * __uint_as_float(u0.x << 16);
        acc.y += w0 * __uint_as_float(u0.x & 0xffff0000u);
        acc.z += w0 * __uint_as_float(u0.y << 16);
        acc.w += w0 * __uint_as_float(u0.y & 0xffff0000u);
      }
    }
  }

  s0 = wred_sum(s0); s1 = wred_sum(s1); s2 = wred_sum(s2);
  float i0 = s0 > 0.f ? 1.f / s0 : 0.f;
  float i1 = s1 > 0.f ? 1.f / s1 : 0.f;
  float i2 = s2 > 0.f ? 1.f / s2 : 0.f;
  float ih = (h == 0) ? i0 : (h == 1) ? i1 : i2;
  acc.x *= ih; acc.y *= ih; acc.z *= ih; acc.w *= ih;

  if (mode == 0) {
    if (l < 48) {
      ushort4 o;
      o.x = f2bf(fmaxf(acc.x, 0.f)); o.y = f2bf(fmaxf(acc.y, 0.f));
      o.z = f2bf(fmaxf(acc.z, 0.f)); o.w = f2bf(fmaxf(acc.w, 0.f));
      *(ushort4*)((unsigned short*)outp + (size_t)n * 192 + l * 4) = o;
    }
  } else {
    float bx = __shfl(acc.x, l + 10, 64), cx = __shfl(acc.x, l + 20, 64);
    float by = __shfl(acc.y, l + 10, 64), cy = __shfl(acc.y, l + 20, 64);
    float bz = __shfl(acc.z, l + 10, 64), cz = __shfl(acc.z, l + 20, 64);
    float bw = __shfl(acc.w, l + 10, 64), cw = __shfl(acc.w, l + 20, 64);
    if (l < 10) {
      float4 o;
      o.x = (acc.x + bx + cx) * (1.f / 3.f);
      o.y = (acc.y + by + cy) * (1.f / 3.f);
      o.z = (acc.z + bz + cz) * (1.f / 3.f);
      o.w = (acc.w + bw + cw) * (1.f / 3.f);
      *(float4*)((float*)outp + (size_t)n * 40 + l * 4) = o;
    }
  }
}

extern "C" void kernel_launch(void* const* d_in, const int* in_sizes, int n_in,
                              void* d_out, int out_size, void* d_ws, size_t ws_size,
                              hipStream_t stream) {
  const float* x   = (const float*)d_in[0];
  const int*   src = (const int*)d_in[1];
  const int*   dst = (const int*)d_in[2];
  const float* W0  = (const float*)d_in[3];
  const float* al0 = (const float*)d_in[4];
  const float* ar0 = (const float*)d_in[5];
  const float* W1  = (const float*)d_in[6];
  const float* al1 = (const float*)d_in[7];
  const float* ar1 = (const float*)d_in[8];
  const float* W2  = (const float*)d_in[9];
  const float* al2 = (const float*)d_in[10];
  const float* ar2 = (const float*)d_in[11];
  const int N = NNODES;
  const int E = in_sizes[1];
  float* out = (float*)d_out;

  char* w = (char*)d_ws;
  unsigned short* xb    = (unsigned short*)w; w += (size_t)N * 256 * 2;  // 25.6MB
  unsigned short* featb = (unsigned short*)w; w += (size_t)N * 192 * 2;  // 19.2MB
  unsigned short* aggb  = (unsigned short*)w; w += (size_t)N * 192 * 2;  // 19.2MB
  unsigned short* Bf    = (unsigned short*)w; w += (size_t)128 * 1024;   // 128KB
  float* elp = (float*)w; w += (size_t)N * 4 * 4;
  float* erp = (float*)w; w += (size_t)N * 4 * 4;
  int* deg = (int*)w; w += (size_t)N * 4;
  int* off = (int*)w; w += (size_t)(N + 1) * 4;
  int* cur = (int*)w; w += (size_t)N * 4;
  int* adj = (int*)w; w += (size_t)E * 4;

  // x -> bf16
  cvt_bf16_kernel<<<(N * 256 / 4 + 255) / 256, 256, 0, stream>>>(x, xb, N * 256 / 4);

  // CSR build (graph static across layers)
  hipMemsetAsync(deg, 0, (size_t)N * 4, stream);
  hipMemsetAsync(cur, 0, (size_t)N * 4, stream);
  count_deg_kernel<<<2048, 256, 0, stream>>>(dst, deg, E);
  scan_kernel<<<1, 1024, 0, stream>>>(deg, off, N);
  fill_adj_kernel<<<2048, 256, 0, stream>>>(src, dst, off, cur, adj, E);

  int gblk = (N + 63) / 64;
  int ablk = (N + 3) / 4;

  // layer 0: K=256, NT=13 (192 feat cols + tile12 = el/er)
  prep_b_kernel<<<(8 * 13 * 64 + 255) / 256, 256, 0, stream>>>(W0, al0, ar0, Bf, 256, 13, 192, 64);
  gemm_mfma_kernel<<<gblk, 256, 0, stream>>>(xb, Bf, featb, elp, erp, N, 256, 13, 192);
  aggregate_kernel<<<ablk, 256, 0, stream>>>(featb, adj, off, elp, erp, aggb, N, 64, 0);
  // layer 1: K=192, NT=13
  prep_b_kernel<<<(6 * 13 * 64 + 255) / 256, 256, 0, stream>>>(W1, al1, ar1, Bf, 192, 13, 192, 64);
  gemm_mfma_kernel<<<gblk, 256, 0, stream>>>(aggb, Bf, featb, elp, erp, N, 192, 13, 192);
  aggregate_kernel<<<ablk, 256, 0, stream>>>(featb, adj, off, elp, erp, aggb, N, 64, 0);
  // layer 2: K=192, NT=8 (120 feat cols + el/er in cols 120..125 of tile 7)
  prep_b_kernel<<<(6 * 8 * 64 + 255) / 256, 256, 0, stream>>>(W2, al2, ar2, Bf, 192, 8, 120, 40);
  gemm_mfma_kernel<<<gblk, 256, 0, stream>>>(aggb, Bf, featb, elp, erp, N, 192, 8, 120);
  aggregate_kernel<<<ablk, 256, 0, stream>>>(featb, adj, off, elp, erp, out, N, 40, 1);
}

// Round 5
// 523.750 us; speedup vs baseline: 1.8789x; 1.2697x over previous
//
#include <hip/hip_runtime.h>

#define NNODES 50000
#define HEADS 3
#define NBUCK 196          // ceil(50000/256)
#define BCAP  16320        // per-bucket edge capacity (avg 8163)

typedef __attribute__((ext_vector_type(8))) short bf16x8;
typedef __attribute__((ext_vector_type(4))) float f32x4;

__device__ __forceinline__ float wred_sum(float v){
  #pragma unroll
  for (int s = 32; s > 0; s >>= 1) v += __shfl_xor(v, s, 64);
  return v;
}
__device__ __forceinline__ unsigned short f2bf(float x){
  unsigned int u = __float_as_uint(x);
  unsigned int r = (u + 0x7FFFu + ((u >> 16) & 1u)) >> 16;
  return (unsigned short)r;
}

// ---------------- x (fp32) -> bf16, vectorized ----------------
__global__ __launch_bounds__(256) void cvt_bf16_kernel(
    const float* __restrict__ in, unsigned short* __restrict__ outb, int n4)
{
  int i = blockIdx.x * 256 + threadIdx.x;
  if (i >= n4) return;
  float4 v = ((const float4*)in)[i];
  ushort4 o;
  o.x = f2bf(v.x); o.y = f2bf(v.y); o.z = f2bf(v.z); o.w = f2bf(v.w);
  ((ushort4*)outb)[i] = o;
}

// ---------------- W -> MFMA-fragment bf16, with folded el/er columns -------
__global__ __launch_bounds__(256) void prep_b_kernel(
    const float* __restrict__ W, const float* __restrict__ al,
    const float* __restrict__ ar, unsigned short* __restrict__ Bf,
    int K, int NT, int NCf, int F)
{
  int tid = blockIdx.x * 256 + threadIdx.x;
  int total = (K >> 5) * NT * 64;
  if (tid >= total) return;
  int l  = tid & 63;
  int t  = (tid >> 6) % NT;
  int kc = tid / (NT * 64);
  int k0  = kc * 32 + (l >> 4) * 8;
  int col = t * 16 + (l & 15);
  unsigned short o[8];
  #pragma unroll
  for (int j = 0; j < 8; ++j) {
    int k = k0 + j;
    float v = 0.f;
    if (col < NCf) {
      v = W[(size_t)k * NCf + col];
    } else if (col < NCf + 6) {
      int c = col - NCf;
      int h = (c < 3) ? c : c - 3;
      const float* av = ((c < 3) ? al : ar) + h * F;
      const float* wp = W + (size_t)k * NCf + h * F;
      float a = 0.f;
      for (int f = 0; f < F; ++f) a += wp[f] * av[f];
      v = a;
    }
    o[j] = f2bf(v);
  }
  ushort4* dst = (ushort4*)&Bf[(size_t)tid * 8];
  dst[0] = make_ushort4(o[0], o[1], o[2], o[3]);
  dst[1] = make_ushort4(o[4], o[5], o[6], o[7]);
}

// ---------------- MFMA GEMM + el/er epilogue ----------------
__global__ __launch_bounds__(256) void gemm_mfma_kernel(
    const unsigned short* __restrict__ Ab, const unsigned short* __restrict__ Bf,
    unsigned short* __restrict__ Cb, float* __restrict__ elp, float* __restrict__ erp,
    int M, int K, int NT, int NCf)
{
  const int w = threadIdx.x >> 6, l = threadIdx.x & 63;
  const int lrow = l & 15, kg = l >> 4;
  const int r0 = blockIdx.x * 64;
  const bf16x8* Bfv = (const bf16x8*)Bf;

  f32x4 acc[4][4];
  #pragma unroll
  for (int mt = 0; mt < 4; ++mt)
    #pragma unroll
    for (int j = 0; j < 4; ++j)
      acc[mt][j] = (f32x4){0.f, 0.f, 0.f, 0.f};

  const int nkc = K >> 5;
  for (int kc = 0; kc < nkc; ++kc) {
    bf16x8 af[4];
    #pragma unroll
    for (int mt = 0; mt < 4; ++mt) {
      int row = r0 + mt * 16 + lrow;
      bf16x8 z = {0,0,0,0,0,0,0,0};
      af[mt] = z;
      if (row < M)
        af[mt] = *(const bf16x8*)&Ab[(size_t)row * K + kc * 32 + kg * 8];
    }
    #pragma unroll
    for (int j = 0; j < 4; ++j) {
      int tile = w + 4 * j;
      if (tile < NT) {
        bf16x8 bfr = Bfv[((size_t)kc * NT + tile) * 64 + l];
        #pragma unroll
        for (int mt = 0; mt < 4; ++mt)
          acc[mt][j] = __builtin_amdgcn_mfma_f32_16x16x32_bf16(af[mt], bfr, acc[mt][j], 0, 0, 0);
      }
    }
  }
  #pragma unroll
  for (int j = 0; j < 4; ++j) {
    int tile = w + 4 * j;
    if (tile >= NT) continue;
    int c = tile * 16 + lrow;
    #pragma unroll
    for (int mt = 0; mt < 4; ++mt) {
      #pragma unroll
      for (int rr = 0; rr < 4; ++rr) {
        int row = r0 + mt * 16 + kg * 4 + rr;
        if (row >= M) continue;
        float v = acc[mt][j][rr];
        if (c < NCf)            Cb[(size_t)row * NCf + c] = f2bf(v);
        else if (c < NCf + 3)   elp[row * 4 + (c - NCf)] = v;
        else if (c < NCf + 6)   erp[row * 4 + (c - NCf - 3)] = v;
      }
    }
  }
}

// ---------------- CSR build: bucket partition ----------------
// Pass 1: bin edges into NBUCK buckets (bucket = dst>>8) with LDS-aggregated
// reservations; writes (src,dst) pairs into per-bucket segments of ebuf.
__global__ __launch_bounds__(256) void partition_kernel(
    const int* __restrict__ src, const int* __restrict__ dst,
    int* __restrict__ bcur, uint2* __restrict__ ebuf, int E)
{
  __shared__ int hist[NBUCK];
  __shared__ int gbase[NBUCK];
  const int t = threadIdx.x;
  const int e0 = blockIdx.x * 2048;
  for (int i = t; i < NBUCK; i += 256) hist[i] = 0;
  __syncthreads();
  int  b_[8], r_[8];
  uint2 p_[8];
  #pragma unroll
  for (int v = 0; v < 8; ++v) {
    int e = e0 + v * 256 + t;
    b_[v] = -1;
    if (e < E) {
      int s = src[e], d = dst[e];
      p_[v] = make_uint2((unsigned)s, (unsigned)d);
      b_[v] = d >> 8;
      r_[v] = atomicAdd(&hist[b_[v]], 1);
    }
  }
  __syncthreads();
  for (int i = t; i < NBUCK; i += 256) {
    int h = hist[i];
    gbase[i] = h ? atomicAdd(&bcur[i], h) : 0;
  }
  __syncthreads();
  #pragma unroll
  for (int v = 0; v < 8; ++v)
    if (b_[v] >= 0)
      ebuf[(size_t)b_[v] * BCAP + gbase[b_[v]] + r_[v]] = p_[v];
}

// Pass 2: exclusive scan of bucket counts (single block)
__global__ __launch_bounds__(256) void bucket_scan_kernel(
    const int* __restrict__ bcur, int* __restrict__ bbase)
{
  __shared__ int wsum[4];
  int t = threadIdx.x, wv = t >> 6, l = t & 63;
  int v = (t < NBUCK) ? bcur[t] : 0;
  int x = v;
  #pragma unroll
  for (int s = 1; s < 64; s <<= 1) {
    int y = __shfl_up(x, s, 64);
    if (l >= s) x += y;
  }
  if (l == 63) wsum[wv] = x;
  __syncthreads();
  int woff = 0;
  #pragma unroll
  for (int k = 0; k < 4; ++k) woff += (k < wv) ? wsum[k] : 0;
  if (t < NBUCK) bbase[t] = woff + x - v;
}

// Pass 3: one WG per bucket. LDS histogram over the 256-node dst range ->
// writes off[] (replaces count_deg+scan), then L2-local scatter into adj.
__global__ __launch_bounds__(256) void fill_local_kernel(
    const uint2* __restrict__ ebuf, const int* __restrict__ bcur,
    const int* __restrict__ bbase, int* __restrict__ off,
    int* __restrict__ adj, int N)
{
  __shared__ int lhist[256], loff[256], lcur[256];
  __shared__ int wsum[4];
  const int b = blockIdx.x;
  const int t = threadIdx.x;
  const int cnt  = bcur[b];
  const int base = bbase[b];
  const uint2* seg = ebuf + (size_t)b * BCAP;
  lhist[t] = 0; lcur[t] = 0;
  __syncthreads();
  for (int i = t; i < cnt; i += 256)
    atomicAdd(&lhist[seg[i].y & 255], 1);
  __syncthreads();
  int wv = t >> 6, l = t & 63;
  int v = lhist[t];
  int x = v;
  #pragma unroll
  for (int s = 1; s < 64; s <<= 1) {
    int y = __shfl_up(x, s, 64);
    if (l >= s) x += y;
  }
  if (l == 63) wsum[wv] = x;
  __syncthreads();
  int woff = 0;
  #pragma unroll
  for (int k = 0; k < 4; ++k) woff += (k < wv) ? wsum[k] : 0;
  loff[t] = woff + x - v;
  int gd = (b << 8) + t;
  if (gd <= N) off[gd] = base + loff[t];
  __syncthreads();
  for (int i = t; i < cnt; i += 256) {
    uint2 p = seg[i];
    int d = p.y & 255;
    int r = atomicAdd(&lcur[d], 1);
    adj[base + loff[d] + r] = (int)p.x;
  }
}

// ---------------- aggregation: one wave per dst node, flash-style ----------
__global__ __launch_bounds__(256) void aggregate_kernel(
    const unsigned short* __restrict__ featb, const int* __restrict__ adj,
    const int* __restrict__ off, const float* __restrict__ elp,
    const float* __restrict__ erp, void* __restrict__ outp,
    int N, int F, int mode)
{
  __shared__ float4 pl[4][64];
  int wv = threadIdx.x >> 6, l = threadIdx.x & 63;
  int n  = blockIdx.x * 4 + wv;
  if (n >= N) return;
  const int NC = HEADS * F;
  const unsigned rowbytes = NC * 2;
  int o0 = off[n], d = off[n + 1] - o0;
  float er0 = erp[n * 4 + 0], er1 = erp[n * 4 + 1], er2 = erp[n * 4 + 2];
  const float4* elv = (const float4*)elp;
  const char* fbase = (const char*)featb;
  const int gl = (F == 64) ? 48 : 30;
  const int h  = (F == 64) ? (l >> 4) : (l / 10);
  const unsigned loff2 = (unsigned)l * 8u;
  const float4* plw = pl[wv];

  float m0 = -1e30f, m1 = -1e30f, m2 = -1e30f;
  float s0 = 0.f, s1 = 0.f, s2 = 0.f;
  float4 acc = {0.f, 0.f, 0.f, 0.f};

  for (int base = 0; base < d; base += 64) {
    int i = base + l;
    float x0 = -1e30f, x1 = -1e30f, x2 = -1e30f;
    unsigned boff = 0;
    if (i < d) {
      int ssrc = adj[o0 + i];
      boff = (unsigned)ssrc * rowbytes;
      float4 ev = elv[ssrc];
      x0 = ev.x + er0; x0 = fmaxf(x0, 0.2f * x0);
      x1 = ev.y + er1; x1 = fmaxf(x1, 0.2f * x1);
      x2 = ev.z + er2; x2 = fmaxf(x2, 0.2f * x2);
    }
    float c0 = x0, c1 = x1, c2 = x2;
    #pragma unroll
    for (int o_ = 32; o_ > 0; o_ >>= 1) {
      c0 = fmaxf(c0, __shfl_xor(c0, o_, 64));
      c1 = fmaxf(c1, __shfl_xor(c1, o_, 64));
      c2 = fmaxf(c2, __shfl_xor(c2, o_, 64));
    }
    float M0 = fmaxf(m0, c0), M1 = fmaxf(m1, c1), M2 = fmaxf(m2, c2);
    float r0 = __expf(m0 - M0), r1 = __expf(m1 - M1), r2 = __expf(m2 - M2);
    s0 *= r0; s1 *= r1; s2 *= r2;
    float rh = (h == 0) ? r0 : (h == 1) ? r1 : r2;
    acc.x *= rh; acc.y *= rh; acc.z *= rh; acc.w *= rh;
    m0 = M0; m1 = M1; m2 = M2;
    float p0 = __expf(x0 - M0), p1 = __expf(x1 - M1), p2 = __expf(x2 - M2);
    s0 += p0; s1 += p1; s2 += p2;
    pl[wv][l] = make_float4(__uint_as_float(boff), p0, p1, p2);

    int cnt = min(64, d - base);
    if (l < gl) {
      int e = 0;
      for (; e + 4 <= cnt; e += 4) {
        float4 a0 = plw[e], a1 = plw[e + 1], a2 = plw[e + 2], a3 = plw[e + 3];
        uint2 u0 = *(const uint2*)(fbase + (__float_as_uint(a0.x) + loff2));
        uint2 u1 = *(const uint2*)(fbase + (__float_as_uint(a1.x) + loff2));
        uint2 u2 = *(const uint2*)(fbase + (__float_as_uint(a2.x) + loff2));
        uint2 u3 = *(const uint2*)(fbase + (__float_as_uint(a3.x) + loff2));
        float w0 = (h == 0) ? a0.y : (h == 1) ? a0.z : a0.w;
        float w1 = (h == 0) ? a1.y : (h == 1) ? a1.z : a1.w;
        float w2 = (h == 0) ? a2.y : (h == 1) ? a2.z : a2.w;
        float w3 = (h == 0) ? a3.y : (h == 1) ? a3.z : a3.w;
        acc.x += w0 * __uint_as_float(u0.x << 16);
        acc.y += w0 * __uint_as_float(u0.x & 0xffff0000u);
        acc.z += w0 * __uint_as_float(u0.y << 16);
        acc.w += w0 * __uint_as_float(u0.y & 0xffff0000u);
        acc.x += w1 * __uint_as_float(u1.x << 16);
        acc.y += w1 * __uint_as_float(u1.x & 0xffff0000u);
        acc.z += w1 * __uint_as_float(u1.y << 16);
        acc.w += w1 * __uint_as_float(u1.y & 0xffff0000u);
        acc.x += w2 * __uint_as_float(u2.x << 16);
        acc.y += w2 * __uint_as_float(u2.x & 0xffff0000u);
        acc.z += w2 * __uint_as_float(u2.y << 16);
        acc.w += w2 * __uint_as_float(u2.y & 0xffff0000u);
        acc.x += w3 * __uint_as_float(u3.x << 16);
        acc.y += w3 * __uint_as_float(u3.x & 0xffff0000u);
        acc.z += w3 * __uint_as_float(u3.y << 16);
        acc.w += w3 * __uint_as_float(u3.y & 0xffff0000u);
      }
      for (; e < cnt; ++e) {
        float4 a0 = plw[e];
        uint2 u0 = *(const uint2*)(fbase + (__float_as_uint(a0.x) + loff2));
        float w0 = (h == 0) ? a0.y : (h == 1) ? a0.z : a0.w;
        acc.x += w0 * __uint_as_float(u0.x << 16);
        acc.y += w0 * __uint_as_float(u0.x & 0xffff0000u);
        acc.z += w0 * __uint_as_float(u0.y << 16);
        acc.w += w0 * __uint_as_float(u0.y & 0xffff0000u);
      }
    }
  }

  s0 = wred_sum(s0); s1 = wred_sum(s1); s2 = wred_sum(s2);
  float i0 = s0 > 0.f ? 1.f / s0 : 0.f;
  float i1 = s1 > 0.f ? 1.f / s1 : 0.f;
  float i2 = s2 > 0.f ? 1.f / s2 : 0.f;
  float ih = (h == 0) ? i0 : (h == 1) ? i1 : i2;
  acc.x *= ih; acc.y *= ih; acc.z *= ih; acc.w *= ih;

  if (mode == 0) {
    if (l < 48) {
      ushort4 o;
      o.x = f2bf(fmaxf(acc.x, 0.f)); o.y = f2bf(fmaxf(acc.y, 0.f));
      o.z = f2bf(fmaxf(acc.z, 0.f)); o.w = f2bf(fmaxf(acc.w, 0.f));
      *(ushort4*)((unsigned short*)outp + (size_t)n * 192 + l * 4) = o;
    }
  } else {
    float bx = __shfl(acc.x, l + 10, 64), cx = __shfl(acc.x, l + 20, 64);
    float by = __shfl(acc.y, l + 10, 64), cy = __shfl(acc.y, l + 20, 64);
    float bz = __shfl(acc.z, l + 10, 64), cz = __shfl(acc.z, l + 20, 64);
    float bw = __shfl(acc.w, l + 10, 64), cw = __shfl(acc.w, l + 20, 64);
    if (l < 10) {
      float4 o;
      o.x = (acc.x + bx + cx) * (1.f / 3.f);
      o.y = (acc.y + by + cy) * (1.f / 3.f);
      o.z = (acc.z + bz + cz) * (1.f / 3.f);
      o.w = (acc.w + bw + cw) * (1.f / 3.f);
      *(float4*)((float*)outp + (size_t)n * 40 + l * 4) = o;
    }
  }
}

extern "C" void kernel_launch(void* const* d_in, const int* in_sizes, int n_in,
                              void* d_out, int out_size, void* d_ws, size_t ws_size,
                              hipStream_t stream) {
  const float* x   = (const float*)d_in[0];
  const int*   src = (const int*)d_in[1];
  const int*   dst = (const int*)d_in[2];
  const float* W0  = (const float*)d_in[3];
  const float* al0 = (const float*)d_in[4];
  const float* ar0 = (const float*)d_in[5];
  const float* W1  = (const float*)d_in[6];
  const float* al1 = (const float*)d_in[7];
  const float* ar1 = (const float*)d_in[8];
  const float* W2  = (const float*)d_in[9];
  const float* al2 = (const float*)d_in[10];
  const float* ar2 = (const float*)d_in[11];
  const int N = NNODES;
  const int E = in_sizes[1];
  float* out = (float*)d_out;

  char* w = (char*)d_ws;
  unsigned short* xb    = (unsigned short*)w; w += (size_t)N * 256 * 2;  // 25.6MB
  unsigned short* featb = (unsigned short*)w; w += (size_t)N * 192 * 2;  // 19.2MB
  unsigned short* aggb  = (unsigned short*)w; w += (size_t)N * 192 * 2;  // 19.2MB
  unsigned short* Bf    = (unsigned short*)w; w += (size_t)128 * 1024;   // 128KB
  float* elp = (float*)w; w += (size_t)N * 4 * 4;
  float* erp = (float*)w; w += (size_t)N * 4 * 4;
  int* off   = (int*)w;  w += (size_t)(N + 1) * 4;
  int* adj   = (int*)w;  w += (size_t)E * 4;
  int* bcur  = (int*)w;  w += (size_t)NBUCK * 4;
  int* bbase = (int*)w;  w += (size_t)NBUCK * 4;
  uint2* ebuf = (uint2*)xb;   // alias: ebuf (25.59MB) dead before xb is written

  // CSR build via bucket partition (all scatters L2-local)
  hipMemsetAsync(bcur, 0, (size_t)NBUCK * 4, stream);
  partition_kernel<<<(E + 2047) / 2048, 256, 0, stream>>>(src, dst, bcur, ebuf, E);
  bucket_scan_kernel<<<1, 256, 0, stream>>>(bcur, bbase);
  fill_local_kernel<<<NBUCK, 256, 0, stream>>>(ebuf, bcur, bbase, off, adj, N);

  // x -> bf16 (after CSR: xb aliases ebuf)
  cvt_bf16_kernel<<<(N * 256 / 4 + 255) / 256, 256, 0, stream>>>(x, xb, N * 256 / 4);

  int gblk = (N + 63) / 64;
  int ablk = (N + 3) / 4;

  // layer 0: K=256, NT=13 (192 feat cols + tile12 = el/er)
  prep_b_kernel<<<(8 * 13 * 64 + 255) / 256, 256, 0, stream>>>(W0, al0, ar0, Bf, 256, 13, 192, 64);
  gemm_mfma_kernel<<<gblk, 256, 0, stream>>>(xb, Bf, featb, elp, erp, N, 256, 13, 192);
  aggregate_kernel<<<ablk, 256, 0, stream>>>(featb, adj, off, elp, erp, aggb, N, 64, 0);
  // layer 1: K=192, NT=13
  prep_b_kernel<<<(6 * 13 * 64 + 255) / 256, 256, 0, stream>>>(W1, al1, ar1, Bf, 192, 13, 192, 64);
  gemm_mfma_kernel<<<gblk, 256, 0, stream>>>(aggb, Bf, featb, elp, erp, N, 192, 13, 192);
  aggregate_kernel<<<ablk, 256, 0, stream>>>(featb, adj, off, elp, erp, aggb, N, 64, 0);
  // layer 2: K=192, NT=8 (120 feat cols + el/er in cols 120..125 of tile 7)
  prep_b_kernel<<<(6 * 8 * 64 + 255) / 256, 256, 0, stream>>>(W2, al2, ar2, Bf, 192, 8, 120, 40);
  gemm_mfma_kernel<<<gblk, 256, 0, stream>>>(aggb, Bf, featb, elp, erp, N, 192, 8, 120);
  aggregate_kernel<<<ablk, 256, 0, stream>>>(featb, adj, off, elp, erp, out, N, 40, 1);
}